// Round 1
// baseline (181.396 us; speedup 1.0000x reference)
//
#include <hip/hip_runtime.h>

#define SEQ_L 512
#define DIM 256

// ---------------------------------------------------------------------------
// Kernel A: out_row = l2norm(X_row @ W + b)
// 8 rows per block, 256 threads (thread t owns output column t).
// ---------------------------------------------------------------------------
__global__ __launch_bounds__(256) void proj_norm_kernel(
    const float* __restrict__ X, const float* __restrict__ W,
    const float* __restrict__ bias, float* __restrict__ out)
{
    const int ROWS = 8;
    __shared__ float xs[ROWS][DIM];
    __shared__ float red[ROWS][4];

    const int t = threadIdx.x;
    const int r0 = blockIdx.x * ROWS;

    #pragma unroll
    for (int r = 0; r < ROWS; ++r)
        xs[r][t] = X[(size_t)(r0 + r) * DIM + t];
    __syncthreads();

    const float b = bias[t];
    float acc[ROWS];
    #pragma unroll
    for (int r = 0; r < ROWS; ++r) acc[r] = b;

    for (int d = 0; d < DIM; ++d) {
        const float wv = W[(size_t)d * DIM + t];   // coalesced across threads
        #pragma unroll
        for (int r = 0; r < ROWS; ++r)
            acc[r] += xs[r][d] * wv;               // xs broadcast (same addr)
    }

    const int lane = t & 63;
    const int wid  = t >> 6;

    #pragma unroll
    for (int r = 0; r < ROWS; ++r) {
        float ss = acc[r] * acc[r];
        #pragma unroll
        for (int off = 32; off >= 1; off >>= 1)
            ss += __shfl_down(ss, off, 64);
        if (lane == 0) red[r][wid] = ss;
    }
    __syncthreads();

    #pragma unroll
    for (int r = 0; r < ROWS; ++r) {
        const float s = red[r][0] + red[r][1] + red[r][2] + red[r][3];
        const float scale = rsqrtf(fmaxf(s, 1e-12f));
        out[(size_t)(r0 + r) * DIM + t] = acc[r] * scale;
    }
}

// ---------------------------------------------------------------------------
// Kernel B: scores[b,l,m] = (0.4*dot(q[b,l],k[b,m]) + 0.6*dot(q[b,l],edge[b,l,m]))/16
// One block (4 waves) per (b,l). Lane i holds q[b,l,4i:4i+4] in a float4.
// Each wave streams edge rows (the 1 GiB HBM stream) coalesced as float4,
// 2 m's in flight per iteration for ILP; wave-shuffle reduction per m.
// ---------------------------------------------------------------------------
__global__ __launch_bounds__(256) void scores_kernel(
    const float* __restrict__ q, const float* __restrict__ k,
    const float* __restrict__ edge, float* __restrict__ out)
{
    const int bl   = blockIdx.x;        // b*SEQ_L + l
    const int b    = bl >> 9;           // / SEQ_L
    const int lane = threadIdx.x & 63;
    const int wave = threadIdx.x >> 6;

    const float4* q4 = (const float4*)(q + (size_t)bl * DIM);
    const float4  qf = q4[lane];

    const float4* k4 = (const float4*)(k + (size_t)b * SEQ_L * DIM);
    const float4* e4 = (const float4*)(edge + (size_t)bl * SEQ_L * DIM);
    float* orow = out + (size_t)bl * SEQ_L;

    for (int m = wave; m < SEQ_L; m += 8) {
        const int m2 = m + 4;
        const float4 kf  = k4[(size_t)m  * 64 + lane];
        const float4 ef  = e4[(size_t)m  * 64 + lane];
        const float4 kf2 = k4[(size_t)m2 * 64 + lane];
        const float4 ef2 = e4[(size_t)m2 * 64 + lane];

        float s  = qf.x * (0.4f * kf.x  + 0.6f * ef.x)
                 + qf.y * (0.4f * kf.y  + 0.6f * ef.y)
                 + qf.z * (0.4f * kf.z  + 0.6f * ef.z)
                 + qf.w * (0.4f * kf.w  + 0.6f * ef.w);
        float s2 = qf.x * (0.4f * kf2.x + 0.6f * ef2.x)
                 + qf.y * (0.4f * kf2.y + 0.6f * ef2.y)
                 + qf.z * (0.4f * kf2.z + 0.6f * ef2.z)
                 + qf.w * (0.4f * kf2.w + 0.6f * ef2.w);

        #pragma unroll
        for (int off = 32; off >= 1; off >>= 1) {
            s  += __shfl_down(s,  off, 64);
            s2 += __shfl_down(s2, off, 64);
        }
        if (lane == 0) {
            orow[m]  = s  * 0.0625f;   // * rsqrt(256)
            orow[m2] = s2 * 0.0625f;
        }
    }
}

// ---------------------------------------------------------------------------
// Host launcher
// ---------------------------------------------------------------------------
extern "C" void kernel_launch(void* const* d_in, const int* in_sizes, int n_in,
                              void* d_out, int out_size, void* d_ws, size_t ws_size,
                              hipStream_t stream) {
    const float* queries = (const float*)d_in[0];
    const float* keys    = (const float*)d_in[1];
    const float* values  = (const float*)d_in[2];
    // d_in[3] = relative_encoding_lookup: DEAD CODE in the reference (its
    // scores_position term is overwritten) -- never read it (saves 1 GiB).
    const float* edge    = (const float*)d_in[4];
    const float* Wq = (const float*)d_in[5];
    const float* bq = (const float*)d_in[6];
    const float* Wk = (const float*)d_in[7];
    const float* bk = (const float*)d_in[8];
    const float* Wv = (const float*)d_in[9];
    const float* bv = (const float*)d_in[10];

    float* out = (float*)d_out;

    const int B = in_sizes[0] / (SEQ_L * DIM);      // 2
    const size_t scores_sz = (size_t)B * SEQ_L * SEQ_L;  // 524288
    const size_t qkv_sz    = (size_t)B * SEQ_L * DIM;    // 262144

    float* v_out = out + scores_sz;           // output slot 1: v
    float* q_out = out + scores_sz + qkv_sz;  // output slot 2: q
    float* k_ws  = (float*)d_ws;              // k is not an output -> scratch

    const int rows  = B * SEQ_L;              // 1024 rows per projection
    const int pblks = rows / 8;               // 128 blocks

    proj_norm_kernel<<<pblks, 256, 0, stream>>>(queries, Wq, bq, q_out);
    proj_norm_kernel<<<pblks, 256, 0, stream>>>(keys,    Wk, bk, k_ws);
    proj_norm_kernel<<<pblks, 256, 0, stream>>>(values,  Wv, bv, v_out);

    scores_kernel<<<rows, 256, 0, stream>>>(q_out, k_ws, edge, out);
}

// Round 2
// 144.858 us; speedup vs baseline: 1.2522x; 1.2522x over previous
//
#include <hip/hip_runtime.h>

#define SEQ_L 512
#define DIM 256

typedef float f4 __attribute__((ext_vector_type(4)));

// ---------------------------------------------------------------------------
// Kernel A: out_row = l2norm(X_row @ W + b) for q/k/v, selected by blockIdx.y.
// 8 rows per block, 256 threads (thread t owns output column t).
// ---------------------------------------------------------------------------
__global__ __launch_bounds__(256) void proj_norm3_kernel(
    const float* __restrict__ Xq, const float* __restrict__ Wq,
    const float* __restrict__ bq, float* __restrict__ oq,
    const float* __restrict__ Xk, const float* __restrict__ Wk,
    const float* __restrict__ bk, float* __restrict__ ok,
    const float* __restrict__ Xv, const float* __restrict__ Wv,
    const float* __restrict__ bv, float* __restrict__ ov)
{
    const float* X; const float* W; const float* bias; float* out;
    if (blockIdx.y == 0)      { X = Xq; W = Wq; bias = bq; out = oq; }
    else if (blockIdx.y == 1) { X = Xk; W = Wk; bias = bk; out = ok; }
    else                      { X = Xv; W = Wv; bias = bv; out = ov; }

    const int ROWS = 8;
    __shared__ float xs[ROWS][DIM];
    __shared__ float red[ROWS][4];

    const int t  = threadIdx.x;
    const int r0 = blockIdx.x * ROWS;

    #pragma unroll
    for (int r = 0; r < ROWS; ++r)
        xs[r][t] = X[(size_t)(r0 + r) * DIM + t];
    __syncthreads();

    const float b = bias[t];
    float acc[ROWS];
    #pragma unroll
    for (int r = 0; r < ROWS; ++r) acc[r] = b;

    for (int d = 0; d < DIM; ++d) {
        const float wv = W[(size_t)d * DIM + t];   // coalesced across threads
        #pragma unroll
        for (int r = 0; r < ROWS; ++r)
            acc[r] += xs[r][d] * wv;               // xs broadcast (same addr)
    }

    const int lane = t & 63;
    const int wid  = t >> 6;

    #pragma unroll
    for (int r = 0; r < ROWS; ++r) {
        float ss = acc[r] * acc[r];
        #pragma unroll
        for (int off = 32; off >= 1; off >>= 1)
            ss += __shfl_down(ss, off, 64);
        if (lane == 0) red[r][wid] = ss;
    }
    __syncthreads();

    #pragma unroll
    for (int r = 0; r < ROWS; ++r) {
        const float s = red[r][0] + red[r][1] + red[r][2] + red[r][3];
        const float scale = rsqrtf(fmaxf(s, 1e-12f));
        out[(size_t)(r0 + r) * DIM + t] = acc[r] * scale;
    }
}

// ---------------------------------------------------------------------------
// Kernel B: scores[b,l,m] = (0.4*dot(q[b,l],k[b,m]) + 0.6*dot(q[b,l],edge[b,l,m]))/16
//
// One block (4 waves) per (b,l) row. 8x8 lane decomposition:
//   lane = d_sub*8 + m_sub  (m_sub = lane&7, d_sub = lane>>3)
// Each wave computes 8 m's at once; lane (d_sub,m_sub) accumulates the
// d-slice [d_sub*4 + 32c .. +3] of row m0+m_sub over c=0..7. One 3-step
// __shfl_xor butterfly (8/16/32) reduces all 8 m's simultaneously:
// 0.375 shuffles per output vs 6 in the previous version.
// Per load instr: 8 rows x 128 contiguous bytes -> fully-used cache lines.
// ---------------------------------------------------------------------------
__global__ __launch_bounds__(256) void scores_kernel(
    const float* __restrict__ q, const float* __restrict__ k,
    const float* __restrict__ edge, float* __restrict__ out)
{
    const int bl    = blockIdx.x;        // b*SEQ_L + l
    const int b     = bl >> 9;           // / SEQ_L
    const int lane  = threadIdx.x & 63;
    const int wave  = threadIdx.x >> 6;
    const int m_sub = lane & 7;
    const int d_sub = lane >> 3;

    // Preload this lane's q slices: qf[c] = q[bl][c*32 + d_sub*4 .. +3]
    const f4* q4 = (const f4*)(q + (size_t)bl * DIM);
    f4 qf[8];
    #pragma unroll
    for (int c = 0; c < 8; ++c) qf[c] = q4[c * 8 + d_sub];

    const f4* k4 = (const f4*)(k + (size_t)b * SEQ_L * DIM);
    const f4* e4 = (const f4*)(edge + (size_t)bl * SEQ_L * DIM);
    float* orow = out + (size_t)bl * SEQ_L;

    for (int m0 = wave * 8; m0 < SEQ_L; m0 += 32) {
        const size_t base = (size_t)(m0 + m_sub) * (DIM / 4) + d_sub;

        float ea = 0.f, eb = 0.f, ka = 0.f, kb = 0.f;
        #pragma unroll
        for (int c = 0; c < 8; ++c) {
            const f4 ef = __builtin_nontemporal_load(&e4[base + c * 8]); // HBM stream
            const f4 kf = k4[base + c * 8];                              // L2-resident
            ea += qf[c].x * ef.x + qf[c].y * ef.y;
            eb += qf[c].z * ef.z + qf[c].w * ef.w;
            ka += qf[c].x * kf.x + qf[c].y * kf.y;
            kb += qf[c].z * kf.z + qf[c].w * kf.w;
        }

        float s = 0.6f * (ea + eb) + 0.4f * (ka + kb);
        s += __shfl_xor(s, 8, 64);
        s += __shfl_xor(s, 16, 64);
        s += __shfl_xor(s, 32, 64);

        if (lane < 8) orow[m0 + lane] = s * 0.0625f;  // * rsqrt(256)
    }
}

// ---------------------------------------------------------------------------
// Host launcher
// ---------------------------------------------------------------------------
extern "C" void kernel_launch(void* const* d_in, const int* in_sizes, int n_in,
                              void* d_out, int out_size, void* d_ws, size_t ws_size,
                              hipStream_t stream) {
    const float* queries = (const float*)d_in[0];
    const float* keys    = (const float*)d_in[1];
    const float* values  = (const float*)d_in[2];
    // d_in[3] = relative_encoding_lookup: DEAD CODE in the reference (its
    // scores_position term is overwritten) -- never read it (saves 1 GiB).
    const float* edge    = (const float*)d_in[4];
    const float* Wq = (const float*)d_in[5];
    const float* bq = (const float*)d_in[6];
    const float* Wk = (const float*)d_in[7];
    const float* bk = (const float*)d_in[8];
    const float* Wv = (const float*)d_in[9];
    const float* bv = (const float*)d_in[10];

    float* out = (float*)d_out;

    const int B = in_sizes[0] / (SEQ_L * DIM);           // 2
    const size_t scores_sz = (size_t)B * SEQ_L * SEQ_L;  // 524288
    const size_t qkv_sz    = (size_t)B * SEQ_L * DIM;    // 262144

    float* v_out = out + scores_sz;           // output slot 1: v
    float* q_out = out + scores_sz + qkv_sz;  // output slot 2: q
    float* k_ws  = (float*)d_ws;              // k is not an output -> scratch

    const int rows = B * SEQ_L;               // 1024 rows per projection

    dim3 pgrid(rows / 8, 3);
    proj_norm3_kernel<<<pgrid, 256, 0, stream>>>(
        queries, Wq, bq, q_out,
        keys,    Wk, bk, k_ws,
        values,  Wv, bv, v_out);

    scores_kernel<<<rows, 256, 0, stream>>>(q_out, k_ws, edge, out);
}

// Round 3
// 127.281 us; speedup vs baseline: 1.4252x; 1.1381x over previous
//
#include <hip/hip_runtime.h>

#define SEQ_L 512
#define DIM 256

typedef float f4 __attribute__((ext_vector_type(4)));

// ---------------------------------------------------------------------------
// Kernel A: out_row = l2norm(X_row @ W + b) for q/k/v, selected by blockIdx.y.
// ---------------------------------------------------------------------------
__global__ __launch_bounds__(256) void proj_norm3_kernel(
    const float* __restrict__ Xq, const float* __restrict__ Wq,
    const float* __restrict__ bq, float* __restrict__ oq,
    const float* __restrict__ Xk, const float* __restrict__ Wk,
    const float* __restrict__ bk, float* __restrict__ ok,
    const float* __restrict__ Xv, const float* __restrict__ Wv,
    const float* __restrict__ bv, float* __restrict__ ov)
{
    const float* X; const float* W; const float* bias; float* out;
    if (blockIdx.y == 0)      { X = Xq; W = Wq; bias = bq; out = oq; }
    else if (blockIdx.y == 1) { X = Xk; W = Wk; bias = bk; out = ok; }
    else                      { X = Xv; W = Wv; bias = bv; out = ov; }

    const int ROWS = 8;
    __shared__ float xs[ROWS][DIM];
    __shared__ float red[ROWS][4];

    const int t  = threadIdx.x;
    const int r0 = blockIdx.x * ROWS;

    #pragma unroll
    for (int r = 0; r < ROWS; ++r)
        xs[r][t] = X[(size_t)(r0 + r) * DIM + t];
    __syncthreads();

    const float b = bias[t];
    float acc[ROWS];
    #pragma unroll
    for (int r = 0; r < ROWS; ++r) acc[r] = b;

    for (int d = 0; d < DIM; ++d) {
        const float wv = W[(size_t)d * DIM + t];
        #pragma unroll
        for (int r = 0; r < ROWS; ++r)
            acc[r] += xs[r][d] * wv;
    }

    const int lane = t & 63;
    const int wid  = t >> 6;

    #pragma unroll
    for (int r = 0; r < ROWS; ++r) {
        float ss = acc[r] * acc[r];
        #pragma unroll
        for (int off = 32; off >= 1; off >>= 1)
            ss += __shfl_down(ss, off, 64);
        if (lane == 0) red[r][wid] = ss;
    }
    __syncthreads();

    #pragma unroll
    for (int r = 0; r < ROWS; ++r) {
        const float s = red[r][0] + red[r][1] + red[r][2] + red[r][3];
        const float scale = rsqrtf(fmaxf(s, 1e-12f));
        out[(size_t)(r0 + r) * DIM + t] = acc[r] * scale;
    }
}

// ---------------------------------------------------------------------------
// Kernel B: out[b,l,m] = 0.025 * dot(q[b,l], k[b,m])   (qk term, L2-resident k)
// 4 l-rows per block -> k traffic amortized 4x. 8x8 lane decomposition +
// 3-step butterfly as before.
// ---------------------------------------------------------------------------
__global__ __launch_bounds__(256) void qk4_kernel(
    const float* __restrict__ q, const float* __restrict__ k,
    float* __restrict__ out)
{
    const int l0    = blockIdx.x * 4;      // 4 rows, same batch (512 % 4 == 0)
    const int b     = l0 >> 9;
    const int lane  = threadIdx.x & 63;
    const int wave  = threadIdx.x >> 6;
    const int m_sub = lane & 7;
    const int d_sub = lane >> 3;

    f4 qf[4][8];
    #pragma unroll
    for (int r = 0; r < 4; ++r) {
        const f4* q4 = (const f4*)(q + (size_t)(l0 + r) * DIM);
        #pragma unroll
        for (int c = 0; c < 8; ++c) qf[r][c] = q4[c * 8 + d_sub];
    }

    const f4* k4 = (const f4*)(k + (size_t)b * SEQ_L * DIM);

    for (int m0 = wave * 8; m0 < SEQ_L; m0 += 32) {
        const size_t base = (size_t)(m0 + m_sub) * (DIM / 4) + d_sub;
        f4 kf[8];
        #pragma unroll
        for (int c = 0; c < 8; ++c) kf[c] = k4[base + c * 8];

        #pragma unroll
        for (int r = 0; r < 4; ++r) {
            float sa = 0.f, sb = 0.f;
            #pragma unroll
            for (int c = 0; c < 8; ++c) {
                sa += qf[r][c].x * kf[c].x + qf[r][c].y * kf[c].y;
                sb += qf[r][c].z * kf[c].z + qf[r][c].w * kf[c].w;
            }
            float s = sa + sb;
            s += __shfl_xor(s, 8, 64);
            s += __shfl_xor(s, 16, 64);
            s += __shfl_xor(s, 32, 64);
            if (lane < 8)
                out[(size_t)(l0 + r) * SEQ_L + m0 + lane] = s * 0.025f;
        }
    }
}

// ---------------------------------------------------------------------------
// Kernel C: out[b,l,m] += 0.0375 * dot(q[b,l], edge[b,l,m])   (HBM stream)
// Pure edge stream: 8 nt-loads per 8-m group, 2 groups unrolled (16 KB in
// flight per wave). Grid (rows, 2): block y-half covers 256 m's.
// ---------------------------------------------------------------------------
__global__ __launch_bounds__(256) void edge_kernel(
    const float* __restrict__ q, const float* __restrict__ edge,
    float* __restrict__ out)
{
    const int bl    = blockIdx.x;
    const int lane  = threadIdx.x & 63;
    const int wave  = threadIdx.x >> 6;
    const int m_sub = lane & 7;
    const int d_sub = lane >> 3;

    const f4* q4 = (const f4*)(q + (size_t)bl * DIM);
    f4 qf[8];
    #pragma unroll
    for (int c = 0; c < 8; ++c) qf[c] = q4[c * 8 + d_sub];

    const f4* e4 = (const f4*)(edge + (size_t)bl * SEQ_L * DIM);
    float* orow = out + (size_t)bl * SEQ_L;

    const int mbase = blockIdx.y * 256;
    for (int m0 = mbase + wave * 8; m0 < mbase + 256; m0 += 64) {
        const int m1 = m0 + 32;
        const size_t ba0 = (size_t)(m0 + m_sub) * (DIM / 4) + d_sub;
        const size_t ba1 = (size_t)(m1 + m_sub) * (DIM / 4) + d_sub;

        f4 e0[8], e1[8];
        #pragma unroll
        for (int c = 0; c < 8; ++c) {
            e0[c] = __builtin_nontemporal_load(&e4[ba0 + c * 8]);
            e1[c] = __builtin_nontemporal_load(&e4[ba1 + c * 8]);
        }

        float base0 = 0.f, base1 = 0.f;
        if (lane < 8) { base0 = orow[m0 + lane]; base1 = orow[m1 + lane]; }

        float sa0 = 0.f, sb0 = 0.f, sa1 = 0.f, sb1 = 0.f;
        #pragma unroll
        for (int c = 0; c < 8; ++c) {
            sa0 += qf[c].x * e0[c].x + qf[c].y * e0[c].y;
            sb0 += qf[c].z * e0[c].z + qf[c].w * e0[c].w;
            sa1 += qf[c].x * e1[c].x + qf[c].y * e1[c].y;
            sb1 += qf[c].z * e1[c].z + qf[c].w * e1[c].w;
        }
        float s0 = sa0 + sb0, s1 = sa1 + sb1;
        s0 += __shfl_xor(s0, 8, 64);  s1 += __shfl_xor(s1, 8, 64);
        s0 += __shfl_xor(s0, 16, 64); s1 += __shfl_xor(s1, 16, 64);
        s0 += __shfl_xor(s0, 32, 64); s1 += __shfl_xor(s1, 32, 64);

        if (lane < 8) {
            orow[m0 + lane] = fmaf(s0, 0.0375f, base0);
            orow[m1 + lane] = fmaf(s1, 0.0375f, base1);
        }
    }
}

// ---------------------------------------------------------------------------
// Host launcher
// ---------------------------------------------------------------------------
extern "C" void kernel_launch(void* const* d_in, const int* in_sizes, int n_in,
                              void* d_out, int out_size, void* d_ws, size_t ws_size,
                              hipStream_t stream) {
    const float* queries = (const float*)d_in[0];
    const float* keys    = (const float*)d_in[1];
    const float* values  = (const float*)d_in[2];
    // d_in[3] = relative_encoding_lookup: DEAD CODE (overwritten in reference).
    const float* edge    = (const float*)d_in[4];
    const float* Wq = (const float*)d_in[5];
    const float* bq = (const float*)d_in[6];
    const float* Wk = (const float*)d_in[7];
    const float* bk = (const float*)d_in[8];
    const float* Wv = (const float*)d_in[9];
    const float* bv = (const float*)d_in[10];

    float* out = (float*)d_out;

    const int B = in_sizes[0] / (SEQ_L * DIM);           // 2
    const size_t scores_sz = (size_t)B * SEQ_L * SEQ_L;
    const size_t qkv_sz    = (size_t)B * SEQ_L * DIM;

    float* v_out = out + scores_sz;           // output slot 1: v
    float* q_out = out + scores_sz + qkv_sz;  // output slot 2: q
    float* k_ws  = (float*)d_ws;              // k -> scratch

    const int rows = B * SEQ_L;               // 1024

    dim3 pgrid(rows / 8, 3);
    proj_norm3_kernel<<<pgrid, 256, 0, stream>>>(
        queries, Wq, bq, q_out,
        keys,    Wk, bk, k_ws,
        values,  Wv, bv, v_out);

    qk4_kernel<<<rows / 4, 256, 0, stream>>>(q_out, k_ws, out);

    dim3 egrid(rows, 2);
    edge_kernel<<<egrid, 256, 0, stream>>>(q_out, edge, out);
}